// Round 1
// baseline (499.577 us; speedup 1.0000x reference)
//
#include <hip/hip_runtime.h>
#include <math.h>

#define BTOT 131072
#define NBK 3
#define SS 16
#define NA 9
#define BAD 25      // SS+NA
#define VD 128
#define CM 10
#define FLAT 75     // NBK*BAD
#define OUTD 51     // NBK*SS + 3
#define EPS 1e-8f

// workspace layout (float offsets)
#define WS_GQK 0
#define WS_GQQ 625
#define WS_GKK 1250
#define WS_V1  1875
#define WS_V2  1900
#define WS_VQ  1925
#define WS_VK  1950
#define WS_C0  1975
#define WS_CQ  1976
#define WS_CK  1977
#define WS_M   1984            // 128*25 = 3200
#define WS_MB  (1984 + 3200)   // 5184, len 128

__device__ __forceinline__ float fast_tanh(float x) {
    x = fminf(fmaxf(x, -15.0f), 15.0f);
    float e = __expf(2.0f * x);
    return (e - 1.0f) / (e + 1.0f);
}

__device__ __forceinline__ float fast_sigmoid(float x) {
    return 1.0f / (1.0f + __expf(-x));
}

// One small block: fold weights into combined operators.
// Gqk = Wq^T Wk, Gqq = Wq^T Wq, Gkk = Wk^T Wk   (25x25 each)
// v1 = Wq^T bk, v2 = Wk^T bq, vq = Wq^T bq, vk = Wk^T bk (25 each)
// c0 = bq.bk, cq = bq.bq, ck = bk.bk
// M = W1 @ Wv (128x25), mb = W1 @ bv + b1 (128)
__global__ void prep_kernel(const float* __restrict__ Wq, const float* __restrict__ bq,
                            const float* __restrict__ Wk, const float* __restrict__ bk,
                            const float* __restrict__ Wv, const float* __restrict__ bv,
                            const float* __restrict__ W1, const float* __restrict__ b1,
                            float* __restrict__ ws) {
    int t = threadIdx.x;  // 256 threads
    for (int idx = t; idx < 625; idx += 256) {
        int e = idx / BAD, f = idx % BAD;
        float gqk = 0.f, gqq = 0.f, gkk = 0.f;
        for (int d = 0; d < VD; ++d) {
            float wqe = Wq[d * BAD + e];
            float wqf = Wq[d * BAD + f];
            float wke = Wk[d * BAD + e];
            float wkf = Wk[d * BAD + f];
            gqk += wqe * wkf;
            gqq += wqe * wqf;
            gkk += wke * wkf;
        }
        ws[WS_GQK + idx] = gqk;
        ws[WS_GQQ + idx] = gqq;
        ws[WS_GKK + idx] = gkk;
    }
    for (int e = t; e < BAD; e += 256) {
        float s1 = 0.f, s2 = 0.f, sq = 0.f, sk = 0.f;
        for (int d = 0; d < VD; ++d) {
            float wqe = Wq[d * BAD + e];
            float wke = Wk[d * BAD + e];
            s1 += wqe * bk[d];
            s2 += wke * bq[d];
            sq += wqe * bq[d];
            sk += wke * bk[d];
        }
        ws[WS_V1 + e] = s1;
        ws[WS_V2 + e] = s2;
        ws[WS_VQ + e] = sq;
        ws[WS_VK + e] = sk;
    }
    if (t == 0) {
        float c0 = 0.f, cq = 0.f, ck = 0.f;
        for (int d = 0; d < VD; ++d) {
            c0 += bq[d] * bk[d];
            cq += bq[d] * bq[d];
            ck += bk[d] * bk[d];
        }
        ws[WS_C0] = c0;
        ws[WS_CQ] = cq;
        ws[WS_CK] = ck;
    }
    for (int idx = t; idx < VD * BAD; idx += 256) {
        int d = idx / BAD, e = idx % BAD;
        float s = 0.f;
        for (int c = 0; c < VD; ++c) s += W1[d * VD + c] * Wv[c * BAD + e];
        ws[WS_M + idx] = s;
    }
    for (int d = t; d < VD; d += 256) {
        float s = b1[d];
        for (int c = 0; c < VD; ++c) s += W1[d * VD + c] * bv[c];
        ws[WS_MB + d] = s;
    }
}

// One thread per batch element.
__global__ __launch_bounds__(256) void main_kernel(
    const float* __restrict__ states, const float* __restrict__ action,
    const int* __restrict__ block_id,
    const float* __restrict__ W2, const float* __restrict__ b2,
    const float* __restrict__ Wc1, const float* __restrict__ bc1,
    const float* __restrict__ Wc2, const float* __restrict__ bc2,
    const float* __restrict__ ws, float* __restrict__ out) {
    int b = blockIdx.x * blockDim.x + threadIdx.x;
    if (b >= BTOT) return;

    const float* st = states + (long)b * (NBK * SS);
    const float* ac = action + (long)b * NA;
    const int* bid = block_id + (long)b * NBK;

    // ---- build ba[3][25] ----
    float ba[NBK * BAD];
    #pragma unroll
    for (int i = 0; i < NBK; ++i) {
        const float4* s4 = (const float4*)(st + i * SS);  // 16B aligned: b*192 + i*64
        #pragma unroll
        for (int w = 0; w < 4; ++w) {
            float4 v = s4[w];
            ba[i * BAD + w * 4 + 0] = v.x;
            ba[i * BAD + w * 4 + 1] = v.y;
            ba[i * BAD + w * 4 + 2] = v.z;
            ba[i * BAD + w * 4 + 3] = v.w;
        }
        bool sel = (bid[i] == 1);
        #pragma unroll
        for (int c = 0; c < NA; ++c)
            ba[i * BAD + SS + c] = sel ? ac[c] : -1.0f;
    }

    // ---- confidence MLP (uses raw ba) ----
    float conf[3];
    {
        float h[CM];
        #pragma unroll
        for (int m = 0; m < CM; ++m) {
            float s = bc1[m];
            #pragma unroll
            for (int e = 0; e < FLAT; ++e) s += Wc1[m * FLAT + e] * ba[e];
            h[m] = fast_sigmoid(s);
        }
        #pragma unroll
        for (int o = 0; o < 3; ++o) {
            float s = bc2[o];
            #pragma unroll
            for (int m = 0; m < CM; ++m) s += Wc2[o * CM + m] * h[m];
            conf[o] = fast_sigmoid(s);
        }
    }

    // ---- attention scores via Gram matrices ----
    const float* Gqk = ws + WS_GQK;
    const float* Gqq = ws + WS_GQQ;
    const float* Gkk = ws + WS_GKK;
    const float* v1 = ws + WS_V1;
    const float* v2 = ws + WS_V2;
    const float* vq = ws + WS_VQ;
    const float* vk = ws + WS_VK;
    float c0 = ws[WS_C0], cq = ws[WS_CQ], ck = ws[WS_CK];

    float s1[NBK], s2[NBK];
    #pragma unroll
    for (int p = 0; p < NBK; ++p) {
        float a1 = 0.f, a2 = 0.f;
        #pragma unroll
        for (int e = 0; e < BAD; ++e) {
            a1 += v1[e] * ba[p * BAD + e];
            a2 += v2[e] * ba[p * BAD + e];
        }
        s1[p] = a1;
        s2[p] = a2;
    }

    float num[NBK][NBK];
    #pragma unroll
    for (int j = 0; j < NBK; ++j) {
        float t[BAD];
        #pragma unroll
        for (int e = 0; e < BAD; ++e) {
            float s = 0.f;
            #pragma unroll
            for (int f = 0; f < BAD; ++f) s += Gqk[e * BAD + f] * ba[j * BAD + f];
            t[e] = s;
        }
        #pragma unroll
        for (int i = 0; i < NBK; ++i) {
            float s = 0.f;
            #pragma unroll
            for (int e = 0; e < BAD; ++e) s += ba[i * BAD + e] * t[e];
            num[i][j] = s + s1[i] + s2[j] + c0;
        }
    }

    float qn2[NBK], kn2[NBK];
    #pragma unroll
    for (int p = 0; p < NBK; ++p) {
        float sq = 0.f, sk = 0.f;
        #pragma unroll
        for (int e = 0; e < BAD; ++e) {
            float tq = 0.f, tk = 0.f;
            #pragma unroll
            for (int f = 0; f < BAD; ++f) {
                tq += Gqq[e * BAD + f] * ba[p * BAD + f];
                tk += Gkk[e * BAD + f] * ba[p * BAD + f];
            }
            sq += ba[p * BAD + e] * tq;
            sk += ba[p * BAD + e] * tk;
        }
        float dq = 0.f, dk = 0.f;
        #pragma unroll
        for (int e = 0; e < BAD; ++e) {
            dq += vq[e] * ba[p * BAD + e];
            dk += vk[e] * ba[p * BAD + e];
        }
        qn2[p] = sq + 2.0f * dq + cq;
        kn2[p] = sk + 2.0f * dk + ck;
    }

    // ---- softmax over j ----
    float att[NBK][NBK];
    #pragma unroll
    for (int i = 0; i < NBK; ++i) {
        float qn = sqrtf(fmaxf(qn2[i], 0.0f));
        float dv[NBK];
        #pragma unroll
        for (int j = 0; j < NBK; ++j) {
            float kn = sqrtf(fmaxf(kn2[j], 0.0f));
            dv[j] = num[i][j] / fmaxf(qn * kn, EPS);
        }
        float mx = fmaxf(dv[0], fmaxf(dv[1], dv[2]));
        float e0 = __expf(dv[0] - mx);
        float e1 = __expf(dv[1] - mx);
        float e2 = __expf(dv[2] - mx);
        float inv = 1.0f / (e0 + e1 + e2);
        att[i][0] = e0 * inv;
        att[i][1] = e1 * inv;
        att[i][2] = e2 * inv;
    }

    // ---- init r2 with base (states) + b2, BEFORE ba is overwritten ----
    float r2[NBK][SS];
    #pragma unroll
    for (int i = 0; i < NBK; ++i)
        #pragma unroll
        for (int o = 0; o < SS; ++o) r2[i][o] = ba[i * BAD + o] + b2[o];

    // ---- a_tilde_i = sum_j att[i][j] * ba_j  (in place) ----
    #pragma unroll
    for (int e = 0; e < BAD; ++e) {
        float b0 = ba[0 * BAD + e], b1v = ba[1 * BAD + e], b2v = ba[2 * BAD + e];
        #pragma unroll
        for (int i = 0; i < NBK; ++i)
            ba[i * BAD + e] = att[i][0] * b0 + att[i][1] * b1v + att[i][2] * b2v;
    }

    // ---- main loop: r1 = tanh(M . a_tilde + mb); r2 += r1 * W2col ----
    const float* M = ws + WS_M;
    const float* mb = ws + WS_MB;
    for (int d = 0; d < VD; ++d) {
        float m0 = mb[d];
        float acc0 = m0, acc1 = m0, acc2 = m0;
        #pragma unroll
        for (int e = 0; e < BAD; ++e) {
            float m = M[d * BAD + e];
            acc0 += m * ba[0 * BAD + e];
            acc1 += m * ba[1 * BAD + e];
            acc2 += m * ba[2 * BAD + e];
        }
        float r10 = fast_tanh(acc0);
        float r11 = fast_tanh(acc1);
        float r12 = fast_tanh(acc2);
        #pragma unroll
        for (int o = 0; o < SS; ++o) {
            float w = W2[o * VD + d];
            r2[0][o] += r10 * w;
            r2[1][o] += r11 * w;
            r2[2][o] += r12 * w;
        }
    }

    // ---- store ----
    float* op = out + (long)b * OUTD;
    #pragma unroll
    for (int i = 0; i < NBK; ++i)
        #pragma unroll
        for (int o = 0; o < SS; ++o) op[i * SS + o] = r2[i][o];
    op[48] = conf[0];
    op[49] = conf[1];
    op[50] = conf[2];
}

extern "C" void kernel_launch(void* const* d_in, const int* in_sizes, int n_in,
                              void* d_out, int out_size, void* d_ws, size_t ws_size,
                              hipStream_t stream) {
    const float* states = (const float*)d_in[0];
    const float* action = (const float*)d_in[1];
    const int* block_id = (const int*)d_in[2];
    const float* Wq = (const float*)d_in[3];
    const float* bq = (const float*)d_in[4];
    const float* Wk = (const float*)d_in[5];
    const float* bk = (const float*)d_in[6];
    const float* Wv = (const float*)d_in[7];
    const float* bv = (const float*)d_in[8];
    const float* W1 = (const float*)d_in[9];
    const float* b1 = (const float*)d_in[10];
    const float* W2 = (const float*)d_in[11];
    const float* b2 = (const float*)d_in[12];
    const float* Wc1 = (const float*)d_in[13];
    const float* bc1 = (const float*)d_in[14];
    const float* Wc2 = (const float*)d_in[15];
    const float* bc2 = (const float*)d_in[16];
    float* out = (float*)d_out;
    float* ws = (float*)d_ws;

    hipLaunchKernelGGL(prep_kernel, dim3(1), dim3(256), 0, stream,
                       Wq, bq, Wk, bk, Wv, bv, W1, b1, ws);
    hipLaunchKernelGGL(main_kernel, dim3(BTOT / 256), dim3(256), 0, stream,
                       states, action, block_id, W2, b2, Wc1, bc1, Wc2, bc2, ws, out);
}